// Round 8
// baseline (289.147 us; speedup 1.0000x reference)
//
#include <hip/hip_runtime.h>
#include <hip/hip_bf16.h>

typedef __attribute__((ext_vector_type(8))) short bf8_t;
typedef __attribute__((ext_vector_type(4))) float f32x4;

#define W_IMG 512
#define H_IMG 512
#define PLANES 96                  // 32 * 3
#define NPIX 25165824.0            // 96 * 512 * 512

#define BR 32                      // out rows per block
#define BC 64                      // out cols per block (16 per wave)
#define HR 56                      // hout row stride (rows 0..47 read; 42..47 zeroed; 16B-aligned cols)
#define MAPW (16 * HR)             // 896 shorts: one map, one wave (16 cols)
#define WVSZ (4 * MAPW)            // 3584 shorts per wave (4 maps)

__global__ void ssim_zero(double* acc) {
    const int t = threadIdx.x;
    if (t < PLANES) acc[t] = 0.0;
}

__global__ void ssim_final(const double* __restrict__ acc, float* __restrict__ out) {
    const int L = threadIdx.x;   // one wave
    double s = (L < PLANES) ? acc[L] : 0.0;
    if (L + 64 < PLANES) s += acc[L + 64];
    #pragma unroll
    for (int off = 32; off > 0; off >>= 1) s += __shfl_down(s, off, 64);
    if (L == 0) out[0] = (float)(1.0 - s / NPIX);
}

// f32 pair -> packed bf16 (RNE), 1 instruction on gfx950
__device__ __forceinline__ unsigned cvtpk(float lo, float hi) {
    unsigned d;
    asm("v_cvt_pk_bf16_f32 %0, %1, %2" : "=v"(d) : "v"(lo), "v"(hi));
    return d;
}

__global__ __launch_bounds__(256)
void ssim_main(const float* __restrict__ img1,
               const float* __restrict__ img2,
               double* __restrict__ acc)
{
    // normalized 11-tap Gaussian, sigma=1.5 (matches reference _create_window)
    constexpr float G[11] = {
        0.00102838f, 0.00759875f, 0.03600077f, 0.10936070f, 0.21300540f,
        0.26601180f,
        0.21300540f, 0.10936070f, 0.03600077f, 0.00759875f, 0.00102838f };
    constexpr float K_C1 = 0.0001f;
    constexpr float K_C2 = 0.0009f;

    // wave-private transposed H-output: [wave][map:{a,b,s2,d2}][col 0..15][row 0..55]
    __shared__ __align__(16) short hw[4 * WVSZ];    // 28,672 B

    const int tid = threadIdx.x;
    const int wv  = tid >> 6;
    const int ln  = tid & 63;
    const int n4  = ln & 15;
    const int q4  = ln >> 4;
    const int kb  = q4 * 8;

    const int tx = blockIdx.x & 7;          // 8 col-tiles of 64
    const int ty = blockIdx.x >> 3;         // 16 row-tiles of 32
    const int c0 = tx * BC;
    const int r0 = ty * BR;
    const int plane = blockIdx.y;
    const size_t pofs = (size_t)plane * (H_IMG * W_IMG);
    const float* __restrict__ p1 = img1 + pofs;
    const float* __restrict__ p2 = img2 + pofs;

    short* __restrict__ hwv = &hw[wv * WVSZ];

    // ---- Toeplitz G fragment (verified in round 7): value(lane,j) = G[kb+j - n4] ----
    // Same registers serve as B for H (B[k][n]=G[k-n]) and A for V (A[m][k]=G[k-m]).
    union UU { unsigned u[4]; bf8_t v; };
    UU GU;
    #pragma unroll
    for (int p = 0; p < 4; ++p) {
        float glo = 0.f, ghi = 0.f;
        #pragma unroll
        for (int t = 0; t < 11; ++t) {
            glo = (kb + 2 * p     - n4 == t) ? G[t] : glo;
            ghi = (kb + 2 * p + 1 - n4 == t) ? G[t] : ghi;
        }
        GU.u[p] = cvtpk(glo, ghi);
    }
    const bf8_t gf = GU.v;
    const f32x4 zz = {0.f, 0.f, 0.f, 0.f};

    // ---- zero pad rows 42..47 (this wave's slice; V's zero-coeff band reads) ----
    {   // 64 lanes = 4 maps x 16 cols, one col each
        short* z = &hwv[(ln >> 4) * MAPW + (ln & 15) * HR + 42];
        *(unsigned*)z = 0u;                   // rows 42,43
        *(uint2*)(z + 2) = make_uint2(0, 0);  // rows 44..47 (8B-aligned)
    }

    // ---- H stage: direct-from-global A-frags, 4 MFMAs per row-chunk ----
    // lane (n4,q4) sources prod row rb+n4, prod cols wv*16+kb .. +7
    // (gc = c0 + wv*16 + kb + j - 5); OOB -> 0 (image zero-padding)
    const int colbase = c0 + wv * 16;
    #pragma unroll
    for (int rbi = 0; rbi < 3; ++rbi) {
        const int rb  = rbi * 16;
        const int gr  = r0 - 5 + rb + n4;
        const int gcs = colbase + kb - 5;
        float a[8], b[8];
        if ((unsigned)gr < (unsigned)H_IMG) {
            const float* q1 = p1 + gr * W_IMG;
            const float* q2 = p2 + gr * W_IMG;
            if (gcs >= 0 && gcs <= W_IMG - 8) {
                float4 x0, x1, y0, y1;
                __builtin_memcpy(&x0, q1 + gcs,     16);
                __builtin_memcpy(&x1, q1 + gcs + 4, 16);
                __builtin_memcpy(&y0, q2 + gcs,     16);
                __builtin_memcpy(&y1, q2 + gcs + 4, 16);
                a[0]=x0.x; a[1]=x0.y; a[2]=x0.z; a[3]=x0.w;
                a[4]=x1.x; a[5]=x1.y; a[6]=x1.z; a[7]=x1.w;
                b[0]=y0.x; b[1]=y0.y; b[2]=y0.z; b[3]=y0.w;
                b[4]=y1.x; b[5]=y1.y; b[6]=y1.z; b[7]=y1.w;
            } else {
                #pragma unroll
                for (int j = 0; j < 8; ++j) {
                    const int g = gcs + j;
                    const bool ok = (unsigned)g < (unsigned)W_IMG;
                    a[j] = ok ? q1[g] : 0.f;
                    b[j] = ok ? q2[g] : 0.f;
                }
            }
        } else {
            #pragma unroll
            for (int j = 0; j < 8; ++j) { a[j] = 0.f; b[j] = 0.f; }
        }

        UU FA, FB, FS, FD;
        #pragma unroll
        for (int p = 0; p < 4; ++p) {
            const float a0 = a[2*p], a1 = a[2*p+1];
            const float b0 = b[2*p], b1 = b[2*p+1];
            FA.u[p] = cvtpk(a0, a1);
            FB.u[p] = cvtpk(b0, b1);
            const float s0 = a0 + b0, s1 = a1 + b1;
            const float e0 = a0 - b0, e1 = a1 - b1;
            FS.u[p] = cvtpk(s0 * s0, s1 * s1);
            FD.u[p] = cvtpk(e0 * e0, e1 * e1);
        }
        f32x4 dA = __builtin_amdgcn_mfma_f32_16x16x32_bf16(FA.v, gf, zz, 0, 0, 0);
        f32x4 dB = __builtin_amdgcn_mfma_f32_16x16x32_bf16(FB.v, gf, zz, 0, 0, 0);
        f32x4 dS = __builtin_amdgcn_mfma_f32_16x16x32_bf16(FS.v, gf, zz, 0, 0, 0);
        f32x4 dD = __builtin_amdgcn_mfma_f32_16x16x32_bf16(FD.v, gf, zz, 0, 0, 0);

        // D row = rb + 4q4 + reg (prod row), col = n4 (out col) -> store transposed
        const int row = rb + 4 * q4;
        #pragma unroll
        for (int mp = 0; mp < 4; ++mp) {
            const f32x4 dd = (mp == 0) ? dA : (mp == 1) ? dB : (mp == 2) ? dS : dD;
            short* hp = &hwv[mp * MAPW + n4 * HR + row];
            const unsigned u0 = cvtpk(dd[0], dd[1]);
            const unsigned u1 = cvtpk(dd[2], dd[3]);
            if (rbi < 2)            *(uint2*)hp = make_uint2(u0, u1);
            else if (q4 < 2)        *(uint2*)hp = make_uint2(u0, u1);
            else if (q4 == 2)       *(unsigned*)hp = u0;     // rows 40,41; 42+ stay zero
        }
    }

    // ---- V stage + SSIM epilogue (reads only this wave's slice; no barrier) ----
    float lsum = 0.f;
    #pragma unroll
    for (int rbi2 = 0; rbi2 < 2; ++rbi2) {
        const int rb2 = rbi2 * 16;
        f32x4 dm[4];
        #pragma unroll
        for (int mp = 0; mp < 4; ++mp) {
            UU BU;
            const uint4 t = *(const uint4*)&hwv[mp * MAPW + n4 * HR + rb2 + kb];
            BU.u[0] = t.x; BU.u[1] = t.y; BU.u[2] = t.z; BU.u[3] = t.w;
            dm[mp] = __builtin_amdgcn_mfma_f32_16x16x32_bf16(gf, BU.v, zz, 0, 0, 0);
        }
        #pragma unroll
        for (int r = 0; r < 4; ++r) {
            const float M1 = dm[0][r], M2 = dm[1][r];
            const float EP = dm[2][r], EM = dm[3][r];
            const float mu12 = M1 * M2;
            const float musq = fmaf(M1, M1, M2 * M2);            // mu1^2 + mu2^2
            const float sig_sum = fmaxf(fmaf(0.5f,  EP + EM, -musq), 0.f);  // s1^2+s2^2
            const float sig12   = fmaf(0.25f, EP - EM, -mu12);
            const float num = fmaf(2.f, mu12, K_C1) * fmaf(2.f, sig12, K_C2);
            const float den = (musq + K_C1) * (sig_sum + K_C2);
            lsum = fmaf(num, __builtin_amdgcn_rcpf(den), lsum);
        }
    }

    // ---- wave reduce -> one atomic per wave into per-plane slot ----
    #pragma unroll
    for (int off = 32; off > 0; off >>= 1)
        lsum += __shfl_down(lsum, off, 64);
    if (ln == 0)
        atomicAdd(&acc[plane], (double)lsum);
}

extern "C" void kernel_launch(void* const* d_in, const int* in_sizes, int n_in,
                              void* d_out, int out_size, void* d_ws, size_t ws_size,
                              hipStream_t stream) {
    const float* img1 = (const float*)d_in[0];
    const float* img2 = (const float*)d_in[1];
    float* out  = (float*)d_out;
    double* acc = (double*)d_ws;   // 96 per-plane accumulators

    ssim_zero<<<dim3(1), dim3(128), 0, stream>>>(acc);
    ssim_main<<<dim3((W_IMG / BC) * (H_IMG / BR), PLANES), dim3(256), 0, stream>>>(img1, img2, acc);
    ssim_final<<<dim3(1), dim3(64), 0, stream>>>(acc, out);
}

// Round 9
// 115.737 us; speedup vs baseline: 2.4983x; 2.4983x over previous
//
#include <hip/hip_runtime.h>

typedef float v2f __attribute__((ext_vector_type(2)));

#define W_IMG 512
#define H_IMG 512
#define PLANES 96                  // 32 * 3
#define NPIX 25165824.0            // 96 * 512 * 512

#define SWIDE 128                  // output cols per wave (2 per lane)
#define SH 64                      // output rows per wave
#define NROWS (SH + 10)            // 74 streamed input rows
#define NQUAD 36                   // staged col-quads per row (144 cols, pad 8 left)
#define NPRS  72                   // staged float4 pair-slots per row
#define XS (W_IMG / SWIDE)         // 4 strips
#define YB (H_IMG / SH)            // 8 bands
#define WPB 2                      // waves per block

__global__ void ssim_zero(double* acc) {
    const int t = threadIdx.x;
    if (t < PLANES) acc[t] = 0.0;
}

__global__ void ssim_final(const double* __restrict__ acc, float* __restrict__ out) {
    const int L = threadIdx.x;   // one wave
    double s = (L < PLANES) ? acc[L] : 0.0;
    if (L + 64 < PLANES) s += acc[L + 64];
    #pragma unroll
    for (int off = 32; off > 0; off >>= 1) s += __shfl_down(s, off, 64);
    if (L == 0) out[0] = (float)(1.0 - s / NPIX);
}

// packed fp32 VOP3P (round-6-proven syntax; fma ties the accumulator)
__device__ __forceinline__ v2f pk_add2(v2f a, v2f b) {
    v2f d; asm("v_pk_add_f32 %0, %1, %2" : "=v"(d) : "v"(a), "v"(b)); return d;
}
__device__ __forceinline__ v2f pk_mul2(v2f a, v2f b) {
    v2f d; asm("v_pk_mul_f32 %0, %1, %2" : "=v"(d) : "v"(a), "v"(b)); return d;
}
__device__ __forceinline__ v2f pk_fma2(v2f a, v2f b, v2f c) {
    asm("v_pk_fma_f32 %0, %1, %2, %0" : "+v"(c) : "v"(a), "v"(b)); return c;
}

__global__ __launch_bounds__(128, 2)
void ssim_main(const float* __restrict__ img1,
               const float* __restrict__ img2,
               double* __restrict__ acc)
{
    // normalized 11-tap Gaussian, sigma=1.5 (matches reference _create_window)
    constexpr float G0=0.00102838f, G1=0.00759875f, G2c=0.03600077f,
                    G3=0.10936070f, G4=0.21300540f, G5=0.26601180f,
                    G6=0.21300540f, G7=0.10936070f, G8=0.03600077f,
                    G9=0.00759875f, G10=0.00102838f;
    constexpr float K_C1 = 0.0001f;
    constexpr float K_C2 = 0.0009f;

    // H coefficient pair-tables (window parity is lane-uniform):
    // px0 uses pairs p=0..5 (taps -1..10), px1 uses pairs p=1..6 (taps 0..11)
    const v2f Gp1[6] = { {0.f,G0}, {G1,G2c}, {G3,G4}, {G5,G6}, {G7,G8}, {G9,G10} };
    const v2f Gp2[6] = { {G0,G1}, {G2c,G3}, {G4,G5}, {G6,G7}, {G8,G9}, {G10,0.f} };
    const v2f GV[11] = { {G0,G0},{G1,G1},{G2c,G2c},{G3,G3},{G4,G4},{G5,G5},
                         {G6,G6},{G7,G7},{G8,G8},{G9,G9},{G10,G10} };

    // per-wave double-buffered row: pair-slot = {a0,a1,b0,b1}
    __shared__ __align__(16) float4 sp[WPB][2][NPRS];

    const int tid = threadIdx.x;
    const int wv  = tid >> 6;
    const int L   = tid & 63;
    const int wid = blockIdx.x * WPB + wv;     // 0..31 per plane
    const int c0  = (wid & (XS - 1)) * SWIDE;
    const int r0  = (wid >> 2) * SH;
    const int plane = blockIdx.y;
    const size_t pofs = (size_t)plane * (H_IMG * W_IMG);
    const float* __restrict__ p1 = img1 + pofs;
    const float* __restrict__ p2 = img2 + pofs;

    // staging: lane < 36 owns quad q=L, global cols c0-8+4L .. +3 (never straddles)
    const int gq  = c0 - 8 + 4 * L;
    const bool qok = (L < NQUAD) && (gq >= 0) && (gq <= W_IMG - 4);
    const bool sth = (L < NQUAD);

    float4 qa = make_float4(0.f,0.f,0.f,0.f), qb = qa;
    auto LOADROW = [&](int s) {
        qa = make_float4(0.f,0.f,0.f,0.f); qb = qa;
        const int gr = r0 - 5 + s;
        if (qok && (unsigned)gr < (unsigned)H_IMG) {
            const int off = gr * W_IMG + gq;
            __builtin_memcpy(&qa, p1 + off, 16);
            __builtin_memcpy(&qb, p2 + off, 16);
        }
    };
    auto STORE = [&](int buf) {
        if (sth) {
            sp[wv][buf][2*L]   = make_float4(qa.x, qa.y, qb.x, qb.y);
            sp[wv][buf][2*L+1] = make_float4(qa.z, qa.w, qb.z, qb.w);
        }
    };

    // rings: 4 maps x 11 rows, each slot = (px0, px1)
    v2f ring_m1[11], ring_m2[11], ring_ab[11], ring_s2[11];
    float lsum = 0.f;
    const v2f z2 = {0.f, 0.f};

    // prologue
    LOADROW(0); STORE(0); LOADROW(1);

    int cur = 0;
    #pragma unroll 1
    for (int sb = 0; sb < 77; sb += 11) {
        #pragma unroll
        for (int j = 0; j < 11; ++j) {
            const int s = sb + j;                 // streamed row; ring slot = j

            if (s + 1 < NROWS) STORE(cur ^ 1);    // row s+1 from regs
            if (s + 2 < NROWS) LOADROW(s + 2);    // prefetch row s+2

            // ---- H: packed 4-map conv on row s (zeros flow through OOB rows) ----
            if (s < NROWS) {
                v2f m1a=z2, m2a=z2, aba=z2, s2a=z2;   // px0
                v2f m1b=z2, m2b=z2, abb=z2, s2b=z2;   // px1
                #pragma unroll
                for (int p = 0; p < 7; ++p) {
                    const float4 P = sp[wv][cur][L + 1 + p];
                    const v2f ap = {P.x, P.y};
                    const v2f bp = {P.z, P.w};
                    const v2f spp = pk_add2(ap, bp);
                    if (p < 6) {
                        const v2f g = Gp1[p];
                        m1a = pk_fma2(g, ap, m1a);
                        m2a = pk_fma2(g, bp, m2a);
                        const v2f t1 = pk_mul2(g, ap);
                        aba = pk_fma2(t1, bp, aba);
                        const v2f t2 = pk_mul2(g, spp);
                        s2a = pk_fma2(t2, spp, s2a);
                    }
                    if (p > 0) {
                        const v2f g = Gp2[p - 1];
                        m1b = pk_fma2(g, ap, m1b);
                        m2b = pk_fma2(g, bp, m2b);
                        const v2f t1 = pk_mul2(g, ap);
                        abb = pk_fma2(t1, bp, abb);
                        const v2f t2 = pk_mul2(g, spp);
                        s2b = pk_fma2(t2, spp, s2b);
                    }
                }
                ring_m1[j] = (v2f){ m1a.x + m1a.y, m1b.x + m1b.y };
                ring_m2[j] = (v2f){ m2a.x + m2a.y, m2b.x + m2b.y };
                ring_ab[j] = (v2f){ aba.x + aba.y, abb.x + abb.y };
                ring_s2[j] = (v2f){ s2a.x + s2a.y, s2b.x + s2b.y };
            }

            // ---- V: packed 11-tap over ring + SSIM for output row s-10 ----
            if (s >= 10 && s < NROWS) {
                v2f M1=z2, M2=z2, AB=z2, S2=z2;
                #pragma unroll
                for (int k = 0; k < 11; ++k) {
                    const int sl = (j + 1 + k) % 11;   // compile-time
                    M1 = pk_fma2(GV[k], ring_m1[sl], M1);
                    M2 = pk_fma2(GV[k], ring_m2[sl], M2);
                    AB = pk_fma2(GV[k], ring_ab[sl], AB);
                    S2 = pk_fma2(GV[k], ring_s2[sl], S2);
                }
                #pragma unroll
                for (int h = 0; h < 2; ++h) {
                    const float u1 = h ? M1.y : M1.x;
                    const float u2 = h ? M2.y : M2.x;
                    const float eab = h ? AB.y : AB.x;
                    const float es2 = h ? S2.y : S2.x;
                    const float mu12 = u1 * u2;
                    const float musq = fmaf(u1, u1, u2 * u2);
                    const float sig12 = eab - mu12;
                    const float sigsum = fmaxf(fmaf(-2.f, eab, es2) - musq, 0.f);
                    const float num = fmaf(2.f, mu12, K_C1) * fmaf(2.f, sig12, K_C2);
                    const float den = (musq + K_C1) * (sigsum + K_C2);
                    lsum = fmaf(num, __builtin_amdgcn_rcpf(den), lsum);
                }
            }

            cur ^= 1;
        }
    }

    // ---- wave reduce -> one atomic per wave into per-plane slot ----
    #pragma unroll
    for (int off = 32; off > 0; off >>= 1)
        lsum += __shfl_down(lsum, off, 64);
    if (L == 0)
        atomicAdd(&acc[plane], (double)lsum);
}

extern "C" void kernel_launch(void* const* d_in, const int* in_sizes, int n_in,
                              void* d_out, int out_size, void* d_ws, size_t ws_size,
                              hipStream_t stream) {
    const float* img1 = (const float*)d_in[0];
    const float* img2 = (const float*)d_in[1];
    float* out  = (float*)d_out;
    double* acc = (double*)d_ws;   // 96 per-plane accumulators

    ssim_zero<<<dim3(1), dim3(128), 0, stream>>>(acc);
    ssim_main<<<dim3(XS * YB / WPB, PLANES), dim3(64 * WPB), 0, stream>>>(img1, img2, acc);
    ssim_final<<<dim3(1), dim3(64), 0, stream>>>(acc, out);
}